// Round 9
// baseline (675.609 us; speedup 1.0000x reference)
//
#include <hip/hip_runtime.h>

#define N_NODES 50000
#define DIM 512
#define N_EDGES 1600000
#define CHSHIFT 12        // 4096-node src chunks = 4 MB of fp16 support = per-XCD L2
#define NCHUNK 13         // ceil(50000 / 4096)
#define CAPC 20           // per-(dst,chunk) capacity; Poisson(2.46) tail negligible
#define DPW 12            // dsts per persistent wave
#define NWAVE 4167        // ceil(50000 / 12) blocks of one wave each

typedef __attribute__((ext_vector_type(8))) short short8;
typedef __attribute__((ext_vector_type(8))) unsigned short ushort8;
typedef __attribute__((ext_vector_type(4))) float floatx4;
typedef __attribute__((ext_vector_type(8))) _Float16 half8;

// ---------------- helpers ----------------
__device__ __forceinline__ unsigned short f2bf(float v) {
    unsigned u = __float_as_uint(v);
    unsigned r = u + 0x7FFF + ((u >> 16) & 1);   // RNE
    return (unsigned short)(r >> 16);
}
__device__ __forceinline__ float bf2f(unsigned short h) {
    return __uint_as_float((unsigned)h << 16);
}
__device__ __forceinline__ void stage16(const char* g, char* l) {
    __builtin_amdgcn_global_load_lds((const __attribute__((address_space(1))) void*)g,
                                     (__attribute__((address_space(3))) void*)l, 16, 0, 0);
}

// -------- convert x -> xh fp16 [N][512], chunk-swizzled per 64-elem block --------
// Eight 16B chunks per block sit at (c ^ (row&7)) — bakes the LDS bank swizzle
// into the global layout for global_load_lds staging. fp16 err 2^-11|x| — better
// than the old bf16-W-limited pipeline (2^-9), so hi/lo concat is unnecessary.
__global__ __launch_bounds__(256) void convert_x(const float* __restrict__ x,
                                                 _Float16* __restrict__ xh) {
    const int t = blockIdx.x * 256 + threadIdx.x;   // one thread = one 8-elem chunk
    if (t >= N_NODES * 64) return;
    const int row = t >> 6;
    const int kc = t & 63;
    const int blk = kc >> 3;
    const int c = kc & 7;
    const int cSw = c ^ (row & 7);

    const floatx4 v0 = __builtin_nontemporal_load((const floatx4*)&x[row * DIM + kc * 8]);
    const floatx4 v1 = __builtin_nontemporal_load((const floatx4*)&x[row * DIM + kc * 8 + 4]);
    const float v[8] = {v0.x, v0.y, v0.z, v0.w, v1.x, v1.y, v1.z, v1.w};
    half8 h;
#pragma unroll
    for (int j = 0; j < 8; j++) h[j] = (_Float16)v[j];
    *(half8*)&xh[row * DIM + blk * 64 + cSw * 8] = h;
}

// -------- convert W [k][n] -> wh [n][512] fp16, swizzled ------------------------
__global__ __launch_bounds__(256) void convert_w(const float* __restrict__ W,
                                                 _Float16* __restrict__ wh) {
    const int t = blockIdx.x * 256 + threadIdx.x;
    if (t >= DIM * 64) return;
    const int n = t >> 6;
    const int kc = t & 63;
    const int blk = kc >> 3;
    const int c = kc & 7;
    const int cSw = c ^ (n & 7);

    half8 h;
#pragma unroll
    for (int j = 0; j < 8; j++) h[j] = (_Float16)W[(kc * 8 + j) * DIM + n];
    *(half8*)&wh[n * DIM + blk * 64 + cSw * 8] = h;
}

// -------- GEMM: support(fp16) = xh @ wh^T, fp16 MFMA, K=512 ---------------------
// 128x128 tile, BK=64, 256 threads = 4 waves (2x2), 8 K-blocks (was 16 with K=1024).
__global__ __launch_bounds__(256, 3) void gemm_f16(const _Float16* __restrict__ A,
                                                   const _Float16* __restrict__ B,
                                                   _Float16* __restrict__ Cb, int M) {
    __shared__ __align__(128) char smem[32768];  // As 16 KB | Bs 16 KB

    const int tid = threadIdx.x;
    const int row0 = blockIdx.y * 128;
    const int col0 = blockIdx.x * 128;

    int srow[4], schk[4];
#pragma unroll
    for (int i = 0; i < 4; i++) {
        const int q = i * 256 + tid;
        srow[i] = q >> 3;          // 0..127
        schk[i] = q & 7;           // stored (already-swizzled) chunk position
    }

    const int l = tid & 63;
    const int w = tid >> 6;
    const int wm = w & 1, wn = w >> 1;
    const int lrow = l & 15;
    const int kg = l >> 4;
    const int s = l & 7;

    int offA[4][2], offB[4][2];
#pragma unroll
    for (int mt = 0; mt < 4; mt++)
#pragma unroll
        for (int h = 0; h < 2; h++) {
            const int chunk = (kg + 4 * h) ^ s;    // undo baked swizzle
            offA[mt][h] = (wm * 64 + mt * 16 + lrow) * 128 + chunk * 16;
            offB[mt][h] = 16384 + (wn * 64 + mt * 16 + lrow) * 128 + chunk * 16;
        }

    floatx4 acc[4][4];
#pragma unroll
    for (int i = 0; i < 4; i++)
#pragma unroll
        for (int j = 0; j < 4; j++) acc[i][j] = (floatx4)(0.f);

    const char* A8 = (const char*)A;
    const char* B8 = (const char*)B;

    for (int kblk = 0; kblk < 8; kblk++) {
        __syncthreads();   // protect LDS from previous iteration's readers
#pragma unroll
        for (int i = 0; i < 4; i++) {
            const int q16 = (i * 256 + tid) * 16;
            const size_t ga = (size_t)min(row0 + srow[i], M - 1) * (DIM * 2)
                              + kblk * 128 + schk[i] * 16;
            const size_t gb = (size_t)(col0 + srow[i]) * (DIM * 2)
                              + kblk * 128 + schk[i] * 16;
            stage16(A8 + ga, smem + q16);
            stage16(B8 + gb, smem + 16384 + q16);
        }
        __syncthreads();   // drains vmcnt -> LDS tiles complete

#pragma unroll
        for (int h = 0; h < 2; h++) {
            half8 bf[4];
#pragma unroll
            for (int nt = 0; nt < 4; nt++) bf[nt] = *(const half8*)(smem + offB[nt][h]);
#pragma unroll
            for (int mt = 0; mt < 4; mt++) {
                const half8 af = *(const half8*)(smem + offA[mt][h]);
#pragma unroll
                for (int nt = 0; nt < 4; nt++)
                    acc[mt][nt] = __builtin_amdgcn_mfma_f32_16x16x32_f16(
                        af, bf[nt], acc[mt][nt], 0, 0, 0);
            }
        }
    }

    // epilogue: C/D layout col = l&15, row = (l>>4)*4 + reg; emit fp16, natural layout
    const int crow0 = row0 + wm * 64;
    const int ccol0 = col0 + wn * 64;
#pragma unroll
    for (int mt = 0; mt < 4; mt++) {
        const int rbase = crow0 + mt * 16 + kg * 4;
#pragma unroll
        for (int nt = 0; nt < 4; nt++) {
            const int cc = ccol0 + nt * 16 + lrow;
#pragma unroll
            for (int r = 0; r < 4; r++) {
                const int gr = rbase + r;
                if (gr < M) Cb[(size_t)gr * DIM + cc] = (_Float16)acc[mt][nt][r];
            }
        }
    }
}

// ------- Edge table build: bucketed by (src-chunk, dst), CHUNK-MAJOR, 4B recs ----
__global__ __launch_bounds__(256) void gcn_build_edges(const int* __restrict__ esrc,
                                                       const int* __restrict__ edst,
                                                       const float* __restrict__ ew,
                                                       int* __restrict__ cursor,
                                                       unsigned int* __restrict__ table) {
    const int e = blockIdx.x * 256 + threadIdx.x;
    if (e >= N_EDGES) return;
    const int d = __builtin_nontemporal_load(&edst[e]);
    const int s = __builtin_nontemporal_load(&esrc[e]);
    const float w = __builtin_nontemporal_load(&ew[e]);
    const int ch = s >> CHSHIFT;                  // 0..12
    const int pos = atomicAdd(&cursor[ch * N_NODES + d], 1);
    if (pos < CAPC) {
        const unsigned rec = (unsigned)s | ((unsigned)f2bf(w) << 16);
        __builtin_nontemporal_store(
            rec, &table[((size_t)ch * N_NODES + d) * CAPC + pos]);
    }
}

// ------- Pack counts: pcntT[c][wave] = 16B vector of 12 u8 segment counts --------
// Replaces 12 dependent cursor loads per chunk-phase with ONE uniform 16B load.
__global__ __launch_bounds__(256) void gcn_pack_counts(const int* __restrict__ cursor,
                                                       unsigned char* __restrict__ pcntT) {
    const int c = blockIdx.y;                         // 0..12
    const int w = blockIdx.x * 256 + threadIdx.x;     // wave id
    if (w >= NWAVE) return;
    unsigned wd[4] = {0, 0, 0, 0};
#pragma unroll
    for (int k = 0; k < DPW; k++) {
        const int dst = w * DPW + k;
        const unsigned cnt = (dst < N_NODES)
            ? (unsigned)min(cursor[c * N_NODES + dst], CAPC) : 0u;
        wd[k >> 2] |= cnt << ((k & 3) * 8);
    }
    uint4 o; o.x = wd[0]; o.y = wd[1]; o.z = wd[2]; o.w = wd[3];
    *(uint4*)(pcntT + ((size_t)c * NWAVE + w) * 16) = o;
}

// -------- Persistent aggregate: L2-chunk sweep, overhead-free segments -----------
// Blocked mapping: wave blk owns dsts blk*12..blk*12+11 -> per phase its 12 table
// segments are one contiguous ~960B run. Counts come from one uniform 16B load.
// fetch floor (r8-verified): 8 XCDs x 51.2 MB support + table ~ 440 MB.
__global__ __launch_bounds__(64, 4) void gcn_aggregate_pers(
        const _Float16* __restrict__ sup,
        const unsigned char* __restrict__ pcntT,
        const unsigned int* __restrict__ table,
        const _Float16* __restrict__ xh,
        const float* __restrict__ b,
        float* __restrict__ out) {
    const int blk = blockIdx.x;    // 0..NWAVE-1
    const int tid = threadIdx.x;   // 0..63
    const int c8 = tid * 8;

    float acc[DPW][8];
#pragma unroll
    for (int k = 0; k < DPW; k++)
#pragma unroll
        for (int j = 0; j < 8; j++) acc[k][j] = 0.f;

    const _Float16* supc = sup + c8;   // lane-fixed column base

    for (int c = 0; c < NCHUNK; c++) {
        const uint4 pcv = *(const uint4*)(pcntT + ((size_t)c * NWAVE + blk) * 16);
        const unsigned pw[4] = {pcv.x, pcv.y, pcv.z, pcv.w};
#pragma unroll
        for (int k = 0; k < DPW; k++) {      // static k -> acc stays in registers
            const int dst = blk * DPW + k;
            const int cnt = (int)((pw[k >> 2] >> ((k & 3) * 8)) & 0xFFu);
            const size_t segbase = ((size_t)c * N_NODES + dst) * CAPC;
#pragma unroll 2
            for (int i = 0; i < cnt; i++) {
                const unsigned rec = table[segbase + i];
                const float wt = bf2f((unsigned short)(rec >> 16));
                const half8 v = *(const half8*)(supc + (size_t)(rec & 0xFFFFu) * DIM);
#pragma unroll
                for (int j = 0; j < 8; j++)
                    acc[k][j] = fmaf(wt, (float)v[j], acc[k][j]);
            }
        }
        // phase fence: memory ops may not cross a chunk boundary at compile time
        asm volatile("" ::: "memory");
    }

    // epilogue: bias + relu + fp16 residual (swizzled xh read), NT store
    const float4 b0 = *(const float4*)&b[c8];
    const float4 b1 = *(const float4*)&b[c8 + 4];
    const float bb[8] = {b0.x, b0.y, b0.z, b0.w, b1.x, b1.y, b1.z, b1.w};
#pragma unroll
    for (int k = 0; k < DPW; k++) {
        const int n = blk * DPW + k;
        if (n >= N_NODES) continue;          // wave-uniform guard (last block only)
        const int xoff = n * DIM + (tid >> 3) * 64 + (((tid & 7) ^ (n & 7)) * 8);
        const half8 xb = *(const half8*)&xh[xoff];
        float o[8];
#pragma unroll
        for (int j = 0; j < 8; j++)
            o[j] = fmaxf(acc[k][j] + bb[j], 0.f) + (float)xb[j];
        floatx4 o0, o1;
        o0.x = o[0]; o0.y = o[1]; o0.z = o[2]; o0.w = o[3];
        o1.x = o[4]; o1.y = o[5]; o1.z = o[6]; o1.w = o[7];
        __builtin_nontemporal_store(o0, (floatx4*)&out[(size_t)n * DIM + c8]);
        __builtin_nontemporal_store(o1, (floatx4*)&out[(size_t)n * DIM + c8 + 4]);
    }
}

extern "C" void kernel_launch(void* const* d_in, const int* in_sizes, int n_in,
                              void* d_out, int out_size, void* d_ws, size_t ws_size,
                              hipStream_t stream) {
    const float* x = (const float*)d_in[0];
    const float* W = (const float*)d_in[1];
    const float* b = (const float*)d_in[2];
    const float* ew = (const float*)d_in[3];
    const int* esrc = (const int*)d_in[4];
    const int* edst = (const int*)d_in[5];
    float* out = (float*)d_out;

    char* ws = (char*)d_ws;
    size_t off = 0;
    _Float16* support = (_Float16*)(ws + off);       off += (size_t)N_NODES * DIM * 2;          // 51.2 MB
    int* cursor = (int*)(ws + off);                  off += (size_t)NCHUNK * N_NODES * 4;       // 2.6 MB
    unsigned int* table = (unsigned int*)(ws + off); off += (size_t)NCHUNK * N_NODES * CAPC * 4;// 52.0 MB
    unsigned char* pcntT = (unsigned char*)(ws + off); off += (size_t)NCHUNK * NWAVE * 16;      // 0.9 MB
    _Float16* xh = (_Float16*)(ws + off);            off += (size_t)N_NODES * DIM * 2;          // 51.2 MB
    _Float16* wh = (_Float16*)(ws + off);            off += (size_t)DIM * DIM * 2;              // 0.5 MB

    (void)hipMemsetAsync(cursor, 0, (size_t)NCHUNK * N_NODES * sizeof(int), stream);

    convert_w<<<(DIM * 64 + 255) / 256, 256, 0, stream>>>(W, wh);
    convert_x<<<(N_NODES * 64 + 255) / 256, 256, 0, stream>>>(x, xh);

    gcn_build_edges<<<(N_EDGES + 255) / 256, 256, 0, stream>>>(esrc, edst, ew,
                                                               cursor, table);
    dim3 pack_grid((NWAVE + 255) / 256, NCHUNK);
    gcn_pack_counts<<<pack_grid, 256, 0, stream>>>(cursor, pcntT);

    dim3 gemm_grid(DIM / 128, (N_NODES + 127) / 128);
    gemm_f16<<<gemm_grid, 256, 0, stream>>>(xh, wh, support, N_NODES);

    gcn_aggregate_pers<<<NWAVE, 64, 0, stream>>>(support, pcntT, table, xh, b, out);
}

// Round 10
// 578.140 us; speedup vs baseline: 1.1686x; 1.1686x over previous
//
#include <hip/hip_runtime.h>

#define N_NODES 50000
#define DIM 512
#define N_EDGES 1600000
#define CHSHIFT 14        // 16384-node src chunks (r7-proven sweet spot)
#define NCHUNK 4          // ceil(50000 / 16384)
#define CAPC 40           // per-(dst,chunk) capacity (r7-proven)
#define PBLK 4096         // persistent grid: 16 blocks/CU x 256 CU, 1 wave each
#define DPW 12            // dsts per persistent wave: PBLK*DPW = 49152
#define TAIL (N_NODES - PBLK * DPW)   // 848 dsts handled by tail kernel

typedef __attribute__((ext_vector_type(8))) short short8;
typedef __attribute__((ext_vector_type(4))) float floatx4;
typedef __attribute__((ext_vector_type(8))) _Float16 half8;

// ---------------- helpers ----------------
__device__ __forceinline__ unsigned short f2bf(float v) {
    unsigned u = __float_as_uint(v);
    unsigned r = u + 0x7FFF + ((u >> 16) & 1);   // RNE
    return (unsigned short)(r >> 16);
}
__device__ __forceinline__ float bf2f(unsigned short h) {
    return __uint_as_float((unsigned)h << 16);
}
__device__ __forceinline__ void stage16(const char* g, char* l) {
    __builtin_amdgcn_global_load_lds((const __attribute__((address_space(1))) void*)g,
                                     (__attribute__((address_space(3))) void*)l, 16, 0, 0);
}

// -------- convert x -> xh fp16 [N][512], chunk-swizzled per 64-elem block --------
// fp16 err 2^-11|x| beats the old bf16-W-limited pipeline (2^-9) => single K=512
// GEMM replaces the hi/lo K=1024 concat (r9-verified: absmax unchanged, -60us).
__global__ __launch_bounds__(256) void convert_x(const float* __restrict__ x,
                                                 _Float16* __restrict__ xh) {
    const int t = blockIdx.x * 256 + threadIdx.x;   // one thread = one 8-elem chunk
    if (t >= N_NODES * 64) return;
    const int row = t >> 6;
    const int kc = t & 63;
    const int blk = kc >> 3;
    const int c = kc & 7;
    const int cSw = c ^ (row & 7);

    const floatx4 v0 = __builtin_nontemporal_load((const floatx4*)&x[row * DIM + kc * 8]);
    const floatx4 v1 = __builtin_nontemporal_load((const floatx4*)&x[row * DIM + kc * 8 + 4]);
    const float v[8] = {v0.x, v0.y, v0.z, v0.w, v1.x, v1.y, v1.z, v1.w};
    half8 h;
#pragma unroll
    for (int j = 0; j < 8; j++) h[j] = (_Float16)v[j];
    *(half8*)&xh[row * DIM + blk * 64 + cSw * 8] = h;
}

// -------- convert W [k][n] -> wh [n][512] fp16, swizzled ------------------------
__global__ __launch_bounds__(256) void convert_w(const float* __restrict__ W,
                                                 _Float16* __restrict__ wh) {
    const int t = blockIdx.x * 256 + threadIdx.x;
    if (t >= DIM * 64) return;
    const int n = t >> 6;
    const int kc = t & 63;
    const int blk = kc >> 3;
    const int c = kc & 7;
    const int cSw = c ^ (n & 7);

    half8 h;
#pragma unroll
    for (int j = 0; j < 8; j++) h[j] = (_Float16)W[(kc * 8 + j) * DIM + n];
    *(half8*)&wh[n * DIM + blk * 64 + cSw * 8] = h;
}

// -------- GEMM: support(fp16) = xh @ wh^T, fp16 MFMA, K=512 ---------------------
// 128x128 tile, BK=64, 256 threads = 4 waves (2x2), 8 K-blocks.
__global__ __launch_bounds__(256, 3) void gemm_f16(const _Float16* __restrict__ A,
                                                   const _Float16* __restrict__ B,
                                                   _Float16* __restrict__ Cb, int M) {
    __shared__ __align__(128) char smem[32768];  // As 16 KB | Bs 16 KB

    const int tid = threadIdx.x;
    const int row0 = blockIdx.y * 128;
    const int col0 = blockIdx.x * 128;

    int srow[4], schk[4];
#pragma unroll
    for (int i = 0; i < 4; i++) {
        const int q = i * 256 + tid;
        srow[i] = q >> 3;          // 0..127
        schk[i] = q & 7;           // stored (already-swizzled) chunk position
    }

    const int l = tid & 63;
    const int w = tid >> 6;
    const int wm = w & 1, wn = w >> 1;
    const int lrow = l & 15;
    const int kg = l >> 4;
    const int s = l & 7;

    int offA[4][2], offB[4][2];
#pragma unroll
    for (int mt = 0; mt < 4; mt++)
#pragma unroll
        for (int h = 0; h < 2; h++) {
            const int chunk = (kg + 4 * h) ^ s;    // undo baked swizzle
            offA[mt][h] = (wm * 64 + mt * 16 + lrow) * 128 + chunk * 16;
            offB[mt][h] = 16384 + (wn * 64 + mt * 16 + lrow) * 128 + chunk * 16;
        }

    floatx4 acc[4][4];
#pragma unroll
    for (int i = 0; i < 4; i++)
#pragma unroll
        for (int j = 0; j < 4; j++) acc[i][j] = (floatx4)(0.f);

    const char* A8 = (const char*)A;
    const char* B8 = (const char*)B;

    for (int kblk = 0; kblk < 8; kblk++) {
        __syncthreads();   // protect LDS from previous iteration's readers
#pragma unroll
        for (int i = 0; i < 4; i++) {
            const int q16 = (i * 256 + tid) * 16;
            const size_t ga = (size_t)min(row0 + srow[i], M - 1) * (DIM * 2)
                              + kblk * 128 + schk[i] * 16;
            const size_t gb = (size_t)(col0 + srow[i]) * (DIM * 2)
                              + kblk * 128 + schk[i] * 16;
            stage16(A8 + ga, smem + q16);
            stage16(B8 + gb, smem + 16384 + q16);
        }
        __syncthreads();   // drains vmcnt -> LDS tiles complete

#pragma unroll
        for (int h = 0; h < 2; h++) {
            half8 bf[4];
#pragma unroll
            for (int nt = 0; nt < 4; nt++) bf[nt] = *(const half8*)(smem + offB[nt][h]);
#pragma unroll
            for (int mt = 0; mt < 4; mt++) {
                const half8 af = *(const half8*)(smem + offA[mt][h]);
#pragma unroll
                for (int nt = 0; nt < 4; nt++)
                    acc[mt][nt] = __builtin_amdgcn_mfma_f32_16x16x32_f16(
                        af, bf[nt], acc[mt][nt], 0, 0, 0);
            }
        }
    }

    // epilogue: C/D layout col = l&15, row = (l>>4)*4 + reg; emit fp16, natural layout
    const int crow0 = row0 + wm * 64;
    const int ccol0 = col0 + wn * 64;
#pragma unroll
    for (int mt = 0; mt < 4; mt++) {
        const int rbase = crow0 + mt * 16 + kg * 4;
#pragma unroll
        for (int nt = 0; nt < 4; nt++) {
            const int cc = ccol0 + nt * 16 + lrow;
#pragma unroll
            for (int r = 0; r < 4; r++) {
                const int gr = rbase + r;
                if (gr < M) Cb[(size_t)gr * DIM + cc] = (_Float16)acc[mt][nt][r];
            }
        }
    }
}

// ------- Edge table build: bucketed by (src-chunk, dst), CHUNK-MAJOR, 4B recs ----
// rec = u16 src | bf16 weight << 16 (r8-verified: absmax unchanged).
__global__ __launch_bounds__(256) void gcn_build_edges(const int* __restrict__ esrc,
                                                       const int* __restrict__ edst,
                                                       const float* __restrict__ ew,
                                                       int* __restrict__ cursor,
                                                       unsigned int* __restrict__ table) {
    const int e = blockIdx.x * 256 + threadIdx.x;
    if (e >= N_EDGES) return;
    const int d = __builtin_nontemporal_load(&edst[e]);
    const int s = __builtin_nontemporal_load(&esrc[e]);
    const float w = __builtin_nontemporal_load(&ew[e]);
    const int ch = s >> CHSHIFT;                  // 0..3
    const int pos = atomicAdd(&cursor[ch * N_NODES + d], 1);
    if (pos < CAPC) {
        const unsigned rec = (unsigned)s | ((unsigned)f2bf(w) << 16);
        __builtin_nontemporal_store(
            rec, &table[((size_t)ch * N_NODES + d) * CAPC + pos]);
    }
}

// -------- shared epilogue: bias + relu + fp16 residual, NT store -----------------
__device__ __forceinline__ void write_node(int n, int tid, const float* acc,
                                           const float* bb,
                                           const _Float16* __restrict__ xh,
                                           float* __restrict__ out) {
    const int c8 = tid * 8;
    const int xoff = n * DIM + (tid >> 3) * 64 + (((tid & 7) ^ (n & 7)) * 8);
    const half8 xb = *(const half8*)&xh[xoff];
    float o[8];
#pragma unroll
    for (int j = 0; j < 8; j++) o[j] = fmaxf(acc[j] + bb[j], 0.f) + (float)xb[j];
    floatx4 o0, o1;
    o0.x = o[0]; o0.y = o[1]; o0.z = o[2]; o0.w = o[3];
    o1.x = o[4]; o1.y = o[5]; o1.z = o[6]; o1.w = o[7];
    __builtin_nontemporal_store(o0, (floatx4*)&out[(size_t)n * DIM + c8]);
    __builtin_nontemporal_store(o1, (floatx4*)&out[(size_t)n * DIM + c8 + 4]);
}

// -------- Persistent aggregate: r7-proven structure (205us), fp16 rows -----------
// Strided dst = w + k*PBLK (inter-wave spread), per-segment cursor loads (compiler
// issues them independently), NCHUNK=4, CAPC=40 (8.3 edges/seg keeps issue rate at
// the measured 3.8 TB/s ceiling; finer chunks collapse it - r4/r8/r9).
__global__ __launch_bounds__(64, 4) void gcn_aggregate_pers(
        const _Float16* __restrict__ sup,
        const int* __restrict__ cursor,
        const unsigned int* __restrict__ table,
        const _Float16* __restrict__ xh,
        const float* __restrict__ b,
        float* __restrict__ out) {
    const int w = blockIdx.x;      // 0..4095
    const int tid = threadIdx.x;   // 0..63
    const int c8 = tid * 8;

    float acc[DPW][8];
#pragma unroll
    for (int k = 0; k < DPW; k++)
#pragma unroll
        for (int j = 0; j < 8; j++) acc[k][j] = 0.f;

    const _Float16* supc = sup + c8;   // lane-fixed column base

    for (int c = 0; c < NCHUNK; c++) {
#pragma unroll
        for (int k = 0; k < DPW; k++) {      // static k -> acc stays in registers
            const int dst = w + k * PBLK;
            const int cnt = min(cursor[c * N_NODES + dst], CAPC);
            const size_t segbase = ((size_t)c * N_NODES + dst) * CAPC;
#pragma unroll 2
            for (int i = 0; i < cnt; i++) {
                const unsigned rec = table[segbase + i];
                const float wt = bf2f((unsigned short)(rec >> 16));
                const half8 v = *(const half8*)(supc + (size_t)(rec & 0xFFFFu) * DIM);
#pragma unroll
                for (int j = 0; j < 8; j++)
                    acc[k][j] = fmaf(wt, (float)v[j], acc[k][j]);
            }
        }
        // phase fence: memory ops may not cross a chunk boundary at compile time
        asm volatile("" ::: "memory");
    }

    const float4 b0 = *(const float4*)&b[c8];
    const float4 b1 = *(const float4*)&b[c8 + 4];
    const float bb[8] = {b0.x, b0.y, b0.z, b0.w, b1.x, b1.y, b1.z, b1.w};
#pragma unroll
    for (int k = 0; k < DPW; k++)
        write_node(w + k * PBLK, tid, acc[k], bb, xh, out);
}

// -------- Tail aggregate: remaining 848 dsts, one wave per dst -------------------
__global__ __launch_bounds__(64) void gcn_aggregate_tail(
        const _Float16* __restrict__ sup,
        const int* __restrict__ cursor,
        const unsigned int* __restrict__ table,
        const _Float16* __restrict__ xh,
        const float* __restrict__ b,
        float* __restrict__ out) {
    const int n = PBLK * DPW + blockIdx.x;   // 49152..49999
    const int tid = threadIdx.x;
    const int c8 = tid * 8;

    float acc[8];
#pragma unroll
    for (int j = 0; j < 8; j++) acc[j] = 0.f;

    const _Float16* supc = sup + c8;

    for (int c = 0; c < NCHUNK; c++) {
        const int cnt = min(cursor[c * N_NODES + n], CAPC);
        const size_t segbase = ((size_t)c * N_NODES + n) * CAPC;
#pragma unroll 2
        for (int i = 0; i < cnt; i++) {
            const unsigned rec = table[segbase + i];
            const float wt = bf2f((unsigned short)(rec >> 16));
            const half8 v = *(const half8*)(supc + (size_t)(rec & 0xFFFFu) * DIM);
#pragma unroll
            for (int j = 0; j < 8; j++) acc[j] = fmaf(wt, (float)v[j], acc[j]);
        }
    }

    const float4 b0 = *(const float4*)&b[c8];
    const float4 b1 = *(const float4*)&b[c8 + 4];
    const float bb[8] = {b0.x, b0.y, b0.z, b0.w, b1.x, b1.y, b1.z, b1.w};
    write_node(n, tid, acc, bb, xh, out);
}

extern "C" void kernel_launch(void* const* d_in, const int* in_sizes, int n_in,
                              void* d_out, int out_size, void* d_ws, size_t ws_size,
                              hipStream_t stream) {
    const float* x = (const float*)d_in[0];
    const float* W = (const float*)d_in[1];
    const float* b = (const float*)d_in[2];
    const float* ew = (const float*)d_in[3];
    const int* esrc = (const int*)d_in[4];
    const int* edst = (const int*)d_in[5];
    float* out = (float*)d_out;

    char* ws = (char*)d_ws;
    size_t off = 0;
    _Float16* support = (_Float16*)(ws + off);       off += (size_t)N_NODES * DIM * 2;           // 51.2 MB
    int* cursor = (int*)(ws + off);                  off += (size_t)NCHUNK * N_NODES * 4;        // 0.8 MB
    unsigned int* table = (unsigned int*)(ws + off); off += (size_t)NCHUNK * N_NODES * CAPC * 4; // 32.0 MB
    _Float16* xh = (_Float16*)(ws + off);            off += (size_t)N_NODES * DIM * 2;           // 51.2 MB
    _Float16* wh = (_Float16*)(ws + off);            off += (size_t)DIM * DIM * 2;               // 0.5 MB

    (void)hipMemsetAsync(cursor, 0, (size_t)NCHUNK * N_NODES * sizeof(int), stream);

    convert_w<<<(DIM * 64 + 255) / 256, 256, 0, stream>>>(W, wh);
    convert_x<<<(N_NODES * 64 + 255) / 256, 256, 0, stream>>>(x, xh);

    gcn_build_edges<<<(N_EDGES + 255) / 256, 256, 0, stream>>>(esrc, edst, ew,
                                                               cursor, table);

    dim3 gemm_grid(DIM / 128, (N_NODES + 127) / 128);
    gemm_f16<<<gemm_grid, 256, 0, stream>>>(xh, wh, support, N_NODES);

    gcn_aggregate_pers<<<PBLK, 64, 0, stream>>>(support, cursor, table, xh, b, out);
    gcn_aggregate_tail<<<TAIL, 64, 0, stream>>>(support, cursor, table, xh, b, out);
}